// Round 17
// baseline (538.949 us; speedup 1.0000x reference)
//
#include <hip/hip_runtime.h>
#include <math.h>

static constexpr int BT  = 512;    // batch
static constexpr int TT  = 2048;   // time steps

// f64-derived constants, cast to f32 exactly as the reference does
static constexpr float C00 = (float)(1000.0 / (1.0 - 0.09));            // D[0][0]
static constexpr float C01 = (float)((1000.0 / (1.0 - 0.09)) * 0.3);    // D[0][1]
static constexpr float C22 = (float)((1000.0 / (1.0 - 0.09)) * 0.35);   // D[2][2]
static constexpr float INV3GH = (float)(1.0 / (3.0 * (1000.0 / 2.6) + 100.0));
static constexpr float SQ3 = 1.7320508075688772f;
static constexpr float IR3 = 0.57735026918962576f;

typedef float f2 __attribute__((ext_vector_type(2)));

__device__ __forceinline__ float softplus_f(float v) {
    return fmaxf(v, 0.0f) + log1pf(expf(-fabsf(v)));
}

// Ballot-driven plastic window (verified R10..R16 flow), exact serial order.
__device__ __forceinline__ void plastic_window(
    float e0, float e1, float e2, int lane,
    float& Pxx, float& Pyy, float& Pxy, float& sigY, float& sigY2,
    float& sxx, float& syy, float& sxy, float& f)
{
    sxx = e0 - Pxx; syy = e1 - Pyy; sxy = e2 - Pxy;
    float q = fmaf(sxy, sxy, 1e-12f);   // sxy sqrt3-scaled
    q = fmaf(syy, syy, q);
    q = fmaf(sxx, sxx - syy, q);
    f = 1.0f;
    unsigned long long mask = __ballot(q > sigY2);
    while (mask) {
        int ts = __ffsll((long long)mask) - 1;
        float qs  = __shfl(q, ts);
        float sxs = __shfl(sxx, ts);
        float sys = __shfl(syy, ts);
        float sps = __shfl(sxy, ts);
        float rq  = __builtin_amdgcn_rsqf(qs);
        float seq = qs * rq;
        float dk  = (seq - sigY) * INV3GH;
        float fn  = fmaf(100.f, dk, sigY);
        float fs  = fn * rq;
        float om  = 1.0f - fs;
        Pxx = fmaf(om, sxs, Pxx);
        Pyy = fmaf(om, sys, Pyy);
        Pxy = fmaf(om, sps, Pxy);
        sigY = fn; sigY2 = fn * fn;
        if (lane == ts) f = fs;
        bool redo = lane > ts;
        if (redo) {
            sxx = e0 - Pxx; syy = e1 - Pyy; sxy = e2 - Pxy;
            q = fmaf(sxy, sxy, 1e-12f);
            q = fmaf(syy, syy, q);
            q = fmaf(sxx, sxx - syy, q);
        }
        mask = __ballot(redo && (q > sigY2));
    }
}

// ---------------------------------------------------------------------------
// R17: R16 structure (direct-global x, red ping-pong, 1 barrier/superstep)
// tuned to cross the 3-blocks/CU occupancy threshold (24 waves/CU):
//  - w2r register cache dropped (-18 VGPR): waves write RAW stress (stride 25,
//    odd -> conflict-free); overlapped reduce does the 24-FMA W2 dot from LDS
//    (w2s reads wave-uniform -> SGPR broadcast).
//  - __launch_bounds__(512, 6) pins VGPR <= 85 (natural use ~86, gentle).
//  - LDS ~32 KB (weights + red[2][2][64*25]) -> 3 blocks/CU fit.
// ---------------------------------------------------------------------------
__global__ __launch_bounds__(512, 6) void k_fused(
    const float* __restrict__ x, const float* __restrict__ W11,
    const float* __restrict__ W12, const float* __restrict__ W2,
    float* __restrict__ out)
{
    __shared__ __align__(16) float w11s[16 * 36];   // [2p+h][36]
    __shared__ __align__(16) float w12d[24 * 36];   // [3p+j][36], D & sqrt3 folded
    __shared__ float w2s[144];                      // softplus(W2), xy col * IR3
    __shared__ float red[2][2][64 * 25];            // [s&1][win][t*25 + p*3 + c]

    const int tid  = threadIdx.x;
    const int lane = tid & 63;     // t within window
    const int wv   = tid >> 6;     // p (0..7)
    const int b    = blockIdx.x;

    // ---- prologue: weights into LDS ----
    if (tid < 512) w11s[(tid >> 5) * 36 + (tid & 31)] = W11[tid];
    if (tid < 256) {
        int i = tid + 512;
        w11s[(i >> 5) * 36 + (i & 31)] = W11[i];
    }
    for (int i = tid; i < 768; i += 512) {
        int r = i >> 5, fc = i & 31;
        int p = r / 3, j = r - p * 3;
        const float* wb = W12 + p * 96 + fc;
        float v;
        if (j == 0)      v = C00 * wb[0]  + C01 * wb[32];
        else if (j == 1) v = C01 * wb[0]  + C00 * wb[32];
        else             v = (C22 * wb[64]) * SQ3;
        w12d[r * 36 + fc] = v;
    }
    if (tid < 144) {
        float v = softplus_f(W2[tid]);
        if ((tid % 24) % 3 == 2) v *= IR3;
        w2s[tid] = v;
    }
    __syncthreads();

    const float4* wa0 = (const float4*)(w11s + (2 * wv) * 36);
    const float4* wa1 = (const float4*)(w11s + (2 * wv + 1) * 36);
    const float4* wb0 = (const float4*)(w12d + (3 * wv) * 36);
    const float4* wb1 = (const float4*)(w12d + (3 * wv + 1) * 36);
    const float4* wb2 = (const float4*)(w12d + (3 * wv + 2) * 36);

    const float4* xg4 = (const float4*)x + (size_t)b * (TT * 8);

    float Pxx = 0.f, Pyy = 0.f, Pxy = 0.f;
    float sigY = 10.f, sigY2 = 100.f, d0 = 0.f;

    for (int s = 0; s < 16; ++s) {
        const int w0 = 2 * s, w1 = w0 + 1;

        // ---- projection of BOTH windows; x direct from global ----
        const float4* xr0 = xg4 + (size_t)(w0 * 64 + lane) * 8;
        const float4* xr1 = xg4 + (size_t)(w1 * 64 + lane) * 8;
        f2 dnA = {0,0}, dsA = {0,0}, e0A = {0,0}, e1A = {0,0}, e2A = {0,0};
        f2 dnB = {0,0}, dsB = {0,0}, e0B = {0,0}, e1B = {0,0}, e2B = {0,0};
        #pragma unroll
        for (int c = 0; c < 8; ++c) {
            float4 xf0 = xr0[c];
            float4 xf1 = xr1[c];
            float4 a0 = wa0[c], a1 = wa1[c];
            float4 b0 = wb0[c], b1 = wb1[c], b2 = wb2[c];
            f2 xlo0 = {xf0.x, xf0.y}, xhi0 = {xf0.z, xf0.w};
            f2 xlo1 = {xf1.x, xf1.y}, xhi1 = {xf1.z, xf1.w};
            f2 t0, t1;
            t0 = (f2){a0.x, a0.y}; t1 = (f2){a0.z, a0.w};
            dnA = xlo0 * t0 + dnA;  dnA = xhi0 * t1 + dnA;
            dnB = xlo1 * t0 + dnB;  dnB = xhi1 * t1 + dnB;
            t0 = (f2){a1.x, a1.y}; t1 = (f2){a1.z, a1.w};
            dsA = xlo0 * t0 + dsA;  dsA = xhi0 * t1 + dsA;
            dsB = xlo1 * t0 + dsB;  dsB = xhi1 * t1 + dsB;
            t0 = (f2){b0.x, b0.y}; t1 = (f2){b0.z, b0.w};
            e0A = xlo0 * t0 + e0A;  e0A = xhi0 * t1 + e0A;
            e0B = xlo1 * t0 + e0B;  e0B = xhi1 * t1 + e0B;
            t0 = (f2){b1.x, b1.y}; t1 = (f2){b1.z, b1.w};
            e1A = xlo0 * t0 + e1A;  e1A = xhi0 * t1 + e1A;
            e1B = xlo1 * t0 + e1B;  e1B = xhi1 * t1 + e1B;
            t0 = (f2){b2.x, b2.y}; t1 = (f2){b2.z, b2.w};
            e2A = xlo0 * t0 + e2A;  e2A = xhi0 * t1 + e2A;
            e2B = xlo1 * t0 + e2B;  e2B = xhi1 * t1 + e2B;
        }
        float dn0 = dnA.x + dnA.y, ds0 = dsA.x + dsA.y;
        float e00 = e0A.x + e0A.y, e10 = e1A.x + e1A.y, e20 = e2A.x + e2A.y;
        float dn1 = dnB.x + dnB.y, ds1 = dsB.x + dsB.y;
        float e01 = e0B.x + e0B.y, e11 = e1B.x + e1B.y, e21 = e2B.x + e2B.y;

        float dnp0  = fmaxf(dn0, 0.f);
        float lam0  = sqrtf(fmaf(dnp0, dnp0, fmaf(ds0, ds0, 1e-12f)));
        float dnew0 = (0.1f * (lam0 - 0.01f)) / (lam0 * 0.09f);
        dnew0 = fminf(fmaxf(dnew0, 0.f), 1.f);
        float dnp1  = fmaxf(dn1, 0.f);
        float lam1  = sqrtf(fmaf(dnp1, dnp1, fmaf(ds1, ds1, 1e-12f)));
        float dnew1 = (0.1f * (lam1 - 0.01f)) / (lam1 * 0.09f);
        dnew1 = fminf(fmaxf(dnew1, 0.f), 1.f);

        // ---- damage max-scans, two windows interleaved (2x ILP) ----
        float m0 = dnew0, m1 = dnew1;
        #pragma unroll
        for (int off = 1; off < 64; off <<= 1) {
            float t0 = __shfl_up(m0, off);
            float t1 = __shfl_up(m1, off);
            if (lane >= off) { m0 = fmaxf(m0, t0); m1 = fmaxf(m1, t1); }
        }
        float de0 = __shfl_up(m0, 1);
        de0 = (lane == 0) ? d0 : fmaxf(d0, de0);
        bool loading0 = dnew0 > de0;
        float di0 = fmaxf(de0, dnew0);
        float d0a = fmaxf(d0, __shfl(m0, 63));     // d after window w0
        float de1 = __shfl_up(m1, 1);
        de1 = (lane == 0) ? d0a : fmaxf(d0a, de1);
        bool loading1 = dnew1 > de1;
        float di1 = fmaxf(de1, dnew1);
        d0 = fmaxf(d0a, __shfl(m1, 63));

        // ---- plastic loops, exact serial order: w0 fully before w1 ----
        float sxx0, syy0, sxy0, f0;
        plastic_window(e00, e10, e20, lane, Pxx, Pyy, Pxy, sigY, sigY2,
                       sxx0, syy0, sxy0, f0);
        float scale0 = loading0 ? f0 : f0 * (1.0f - di0);

        float sxx1, syy1, sxy1, f1;
        plastic_window(e01, e11, e21, lane, Pxx, Pyy, Pxy, sigY, sigY2,
                       sxx1, syy1, sxy1, f1);
        float scale1 = loading1 ? f1 : f1 * (1.0f - di1);

        // ---- raw damaged stress -> red (stride 25, conflict-free) ----
        {
            float* r0 = &red[s & 1][0][lane * 25 + wv * 3];
            r0[0] = scale0 * sxx0; r0[1] = scale0 * syy0; r0[2] = scale0 * sxy0;
            float* r1 = &red[s & 1][1][lane * 25 + wv * 3];
            r1[0] = scale1 * sxx1; r1[1] = scale1 * syy1; r1[2] = scale1 * sxy1;
        }

        // ---- overlapped reduce of PREVIOUS superstep (24-FMA W2 dot) ----
        if (s > 0 && tid < 384) {
            int t = tid & 63, k = tid >> 6;
            int pp = (s - 1) & 1;
            const float* wk = &w2s[k * 24];
            const float* rp0 = &red[pp][0][t * 25];
            float a0 = 0.f;
            #pragma unroll
            for (int j = 0; j < 24; ++j) a0 = fmaf(rp0[j], wk[j], a0);
            out[((size_t)b * TT + (w0 - 2) * 64 + t) * 6 + k] = a0;
            const float* rp1 = &red[pp][1][t * 25];
            float a1 = 0.f;
            #pragma unroll
            for (int j = 0; j < 24; ++j) a1 = fmaf(rp1[j], wk[j], a1);
            out[((size_t)b * TT + (w1 - 2) * 64 + t) * 6 + k] = a1;
        }
        __syncthreads();   // the ONLY barrier per superstep
    }

    // epilogue: reduce superstep 15 (windows 30, 31)
    if (tid < 384) {
        int t = tid & 63, k = tid >> 6;
        const float* wk = &w2s[k * 24];
        const float* rp0 = &red[1][0][t * 25];
        float a0 = 0.f;
        #pragma unroll
        for (int j = 0; j < 24; ++j) a0 = fmaf(rp0[j], wk[j], a0);
        out[((size_t)b * TT + 30 * 64 + t) * 6 + k] = a0;
        const float* rp1 = &red[1][1][t * 25];
        float a1 = 0.f;
        #pragma unroll
        for (int j = 0; j < 24; ++j) a1 = fmaf(rp1[j], wk[j], a1);
        out[((size_t)b * TT + 31 * 64 + t) * 6 + k] = a1;
    }
}

extern "C" void kernel_launch(void* const* d_in, const int* in_sizes, int n_in,
                              void* d_out, int out_size, void* d_ws, size_t ws_size,
                              hipStream_t stream)
{
    const float* x   = (const float*)d_in[0];
    const float* W11 = (const float*)d_in[1];
    const float* W12 = (const float*)d_in[2];
    const float* W2  = (const float*)d_in[3];
    float* out = (float*)d_out;

    hipLaunchKernelGGL(k_fused, dim3(BT), dim3(512), 0, stream,
                       x, W11, W12, W2, out);
}

// Round 18
// 123.800 us; speedup vs baseline: 4.3534x; 4.3534x over previous
//
#include <hip/hip_runtime.h>
#include <math.h>

static constexpr int BT  = 512;    // batch
static constexpr int TT  = 2048;   // time steps

// f64-derived constants, cast to f32 exactly as the reference does
static constexpr float C00 = (float)(1000.0 / (1.0 - 0.09));            // D[0][0]
static constexpr float C01 = (float)((1000.0 / (1.0 - 0.09)) * 0.3);    // D[0][1]
static constexpr float C22 = (float)((1000.0 / (1.0 - 0.09)) * 0.35);   // D[2][2]
static constexpr float INV3GH = (float)(1.0 / (3.0 * (1000.0 / 2.6) + 100.0));
static constexpr float SQ3 = 1.7320508075688772f;
static constexpr float IR3 = 0.57735026918962576f;

typedef float f2 __attribute__((ext_vector_type(2)));

__device__ __forceinline__ float softplus_f(float v) {
    return fmaxf(v, 0.0f) + log1pf(expf(-fabsf(v)));
}

// Ballot-driven plastic window (verified R10..R16 flow), exact serial order.
__device__ __forceinline__ void plastic_window(
    float e0, float e1, float e2, int lane,
    float& Pxx, float& Pyy, float& Pxy, float& sigY, float& sigY2,
    float& sxx, float& syy, float& sxy, float& f)
{
    sxx = e0 - Pxx; syy = e1 - Pyy; sxy = e2 - Pxy;
    float q = fmaf(sxy, sxy, 1e-12f);   // sxy sqrt3-scaled
    q = fmaf(syy, syy, q);
    q = fmaf(sxx, sxx - syy, q);
    f = 1.0f;
    unsigned long long mask = __ballot(q > sigY2);
    while (mask) {
        int ts = __ffsll((long long)mask) - 1;
        float qs  = __shfl(q, ts);
        float sxs = __shfl(sxx, ts);
        float sys = __shfl(syy, ts);
        float sps = __shfl(sxy, ts);
        float rq  = __builtin_amdgcn_rsqf(qs);
        float seq = qs * rq;
        float dk  = (seq - sigY) * INV3GH;
        float fn  = fmaf(100.f, dk, sigY);
        float fs  = fn * rq;
        float om  = 1.0f - fs;
        Pxx = fmaf(om, sxs, Pxx);
        Pyy = fmaf(om, sys, Pyy);
        Pxy = fmaf(om, sps, Pxy);
        sigY = fn; sigY2 = fn * fn;
        if (lane == ts) f = fs;
        bool redo = lane > ts;
        if (redo) {
            sxx = e0 - Pxx; syy = e1 - Pyy; sxy = e2 - Pxy;
            q = fmaf(sxy, sxy, 1e-12f);
            q = fmaf(syy, syy, q);
            q = fmaf(sxx, sxx - syy, q);
        }
        mask = __ballot(redo && (q > sigY2));
    }
}

// ---------------------------------------------------------------------------
// R18 = R15 (verified best: LDS-staged x, 2-window superstep, NO launch-bounds
// squeeze) + ONE barrier per superstep:
//  - red ping-pong across supersteps, raw stress (stride 25, odd ->
//    conflict-free): red[s&1][win][t*25 + p*3 + c]
//  - overlapped reduce of superstep s-1 does the 24-FMA W2 dot from LDS
//    (w2s wave-uniform); w2r register cache dropped (VGPR 108 -> ~90).
// LDS ~68.8 KB -> still 2 blocks/CU.
// ---------------------------------------------------------------------------
__global__ __launch_bounds__(512) void k_fused(
    const float* __restrict__ x, const float* __restrict__ W11,
    const float* __restrict__ W12, const float* __restrict__ W2,
    float* __restrict__ out)
{
    __shared__ __align__(16) float w11s[16 * 36];   // [2p+h][36]
    __shared__ __align__(16) float w12d[24 * 36];   // [3p+j][36], D & sqrt3 folded
    __shared__ float w2s[144];                      // softplus(W2), xy col * IR3
    __shared__ __align__(16) float xs[4][64 * 36];  // 4-deep x window ring
    __shared__ float red[2][2][64 * 25];            // [s&1][win][t*25 + p*3 + c]

    const int tid  = threadIdx.x;
    const int lane = tid & 63;     // t within window
    const int wv   = tid >> 6;     // p (0..7)
    const int b    = blockIdx.x;

    // ---- prologue: weights into LDS ----
    if (tid < 512) w11s[(tid >> 5) * 36 + (tid & 31)] = W11[tid];
    if (tid < 256) {
        int i = tid + 512;
        w11s[(i >> 5) * 36 + (i & 31)] = W11[i];
    }
    for (int i = tid; i < 768; i += 512) {
        int r = i >> 5, fc = i & 31;
        int p = r / 3, j = r - p * 3;
        const float* wb = W12 + p * 96 + fc;
        float v;
        if (j == 0)      v = C00 * wb[0]  + C01 * wb[32];
        else if (j == 1) v = C01 * wb[0]  + C00 * wb[32];
        else             v = (C22 * wb[64]) * SQ3;
        w12d[r * 36 + fc] = v;
    }
    if (tid < 144) {
        float v = softplus_f(W2[tid]);
        if ((tid % 24) % 3 == 2) v *= IR3;
        w2s[tid] = v;
    }
    // stage windows 0 and 1
    const float4* xg4 = (const float4*)x + (size_t)b * (TT * 8);
    {
        int t = tid >> 3, c = tid & 7;
        float4 v0 = xg4[tid];
        float4 v1 = xg4[512 + tid];
        *(float4*)&xs[0][t * 36 + 4 * c] = v0;
        *(float4*)&xs[1][t * 36 + 4 * c] = v1;
    }
    __syncthreads();

    const float4* wa0 = (const float4*)(w11s + (2 * wv) * 36);
    const float4* wa1 = (const float4*)(w11s + (2 * wv + 1) * 36);
    const float4* wb0 = (const float4*)(w12d + (3 * wv) * 36);
    const float4* wb1 = (const float4*)(w12d + (3 * wv + 1) * 36);
    const float4* wb2 = (const float4*)(w12d + (3 * wv + 2) * 36);

    float Pxx = 0.f, Pyy = 0.f, Pxy = 0.f;
    float sigY = 10.f, sigY2 = 100.f, d0 = 0.f;

    for (int s = 0; s < 16; ++s) {
        const int w0 = 2 * s, w1 = w0 + 1;
        const bool have = (s < 15);
        float4 nv0, nv1;
        if (have) {
            nv0 = xg4[(w0 + 2) * 512 + tid];
            nv1 = xg4[(w1 + 2) * 512 + tid];
        }

        // ---- projection of BOTH windows, shared weight reads ----
        const float* xr0 = &xs[w0 & 3][lane * 36];
        const float* xr1 = &xs[w1 & 3][lane * 36];
        f2 dnA = {0,0}, dsA = {0,0}, e0A = {0,0}, e1A = {0,0}, e2A = {0,0};
        f2 dnB = {0,0}, dsB = {0,0}, e0B = {0,0}, e1B = {0,0}, e2B = {0,0};
        #pragma unroll
        for (int c = 0; c < 8; ++c) {
            float4 a0 = wa0[c], a1 = wa1[c];
            float4 b0 = wb0[c], b1 = wb1[c], b2 = wb2[c];
            float4 xf0 = *(const float4*)(xr0 + 4 * c);
            float4 xf1 = *(const float4*)(xr1 + 4 * c);
            f2 xlo0 = {xf0.x, xf0.y}, xhi0 = {xf0.z, xf0.w};
            f2 xlo1 = {xf1.x, xf1.y}, xhi1 = {xf1.z, xf1.w};
            f2 t0, t1;
            t0 = (f2){a0.x, a0.y}; t1 = (f2){a0.z, a0.w};
            dnA = xlo0 * t0 + dnA;  dnA = xhi0 * t1 + dnA;
            dnB = xlo1 * t0 + dnB;  dnB = xhi1 * t1 + dnB;
            t0 = (f2){a1.x, a1.y}; t1 = (f2){a1.z, a1.w};
            dsA = xlo0 * t0 + dsA;  dsA = xhi0 * t1 + dsA;
            dsB = xlo1 * t0 + dsB;  dsB = xhi1 * t1 + dsB;
            t0 = (f2){b0.x, b0.y}; t1 = (f2){b0.z, b0.w};
            e0A = xlo0 * t0 + e0A;  e0A = xhi0 * t1 + e0A;
            e0B = xlo1 * t0 + e0B;  e0B = xhi1 * t1 + e0B;
            t0 = (f2){b1.x, b1.y}; t1 = (f2){b1.z, b1.w};
            e1A = xlo0 * t0 + e1A;  e1A = xhi0 * t1 + e1A;
            e1B = xlo1 * t0 + e1B;  e1B = xhi1 * t1 + e1B;
            t0 = (f2){b2.x, b2.y}; t1 = (f2){b2.z, b2.w};
            e2A = xlo0 * t0 + e2A;  e2A = xhi0 * t1 + e2A;
            e2B = xlo1 * t0 + e2B;  e2B = xhi1 * t1 + e2B;
        }
        float dn0 = dnA.x + dnA.y, ds0 = dsA.x + dsA.y;
        float e00 = e0A.x + e0A.y, e10 = e1A.x + e1A.y, e20 = e2A.x + e2A.y;
        float dn1 = dnB.x + dnB.y, ds1 = dsB.x + dsB.y;
        float e01 = e0B.x + e0B.y, e11 = e1B.x + e1B.y, e21 = e2B.x + e2B.y;

        float dnp0  = fmaxf(dn0, 0.f);
        float lam0  = sqrtf(fmaf(dnp0, dnp0, fmaf(ds0, ds0, 1e-12f)));
        float dnew0 = (0.1f * (lam0 - 0.01f)) / (lam0 * 0.09f);
        dnew0 = fminf(fmaxf(dnew0, 0.f), 1.f);
        float dnp1  = fmaxf(dn1, 0.f);
        float lam1  = sqrtf(fmaf(dnp1, dnp1, fmaf(ds1, ds1, 1e-12f)));
        float dnew1 = (0.1f * (lam1 - 0.01f)) / (lam1 * 0.09f);
        dnew1 = fminf(fmaxf(dnew1, 0.f), 1.f);

        // ---- damage max-scans, two windows interleaved (2x ILP) ----
        float m0 = dnew0, m1 = dnew1;
        #pragma unroll
        for (int off = 1; off < 64; off <<= 1) {
            float t0 = __shfl_up(m0, off);
            float t1 = __shfl_up(m1, off);
            if (lane >= off) { m0 = fmaxf(m0, t0); m1 = fmaxf(m1, t1); }
        }
        float de0 = __shfl_up(m0, 1);
        de0 = (lane == 0) ? d0 : fmaxf(d0, de0);
        bool loading0 = dnew0 > de0;
        float di0 = fmaxf(de0, dnew0);
        float d0a = fmaxf(d0, __shfl(m0, 63));     // d after window w0
        float de1 = __shfl_up(m1, 1);
        de1 = (lane == 0) ? d0a : fmaxf(d0a, de1);
        bool loading1 = dnew1 > de1;
        float di1 = fmaxf(de1, dnew1);
        d0 = fmaxf(d0a, __shfl(m1, 63));

        // ---- plastic loops, exact serial order: w0 fully before w1 ----
        float sxx0, syy0, sxy0, f0;
        plastic_window(e00, e10, e20, lane, Pxx, Pyy, Pxy, sigY, sigY2,
                       sxx0, syy0, sxy0, f0);
        float scale0 = loading0 ? f0 : f0 * (1.0f - di0);

        float sxx1, syy1, sxy1, f1;
        plastic_window(e01, e11, e21, lane, Pxx, Pyy, Pxy, sigY, sigY2,
                       sxx1, syy1, sxy1, f1);
        float scale1 = loading1 ? f1 : f1 * (1.0f - di1);

        // ---- raw damaged stress -> red (stride 25, conflict-free) ----
        {
            float* r0 = &red[s & 1][0][lane * 25 + wv * 3];
            r0[0] = scale0 * sxx0; r0[1] = scale0 * syy0; r0[2] = scale0 * sxy0;
            float* r1 = &red[s & 1][1][lane * 25 + wv * 3];
            r1[0] = scale1 * sxx1; r1[1] = scale1 * syy1; r1[2] = scale1 * sxy1;
        }

        // ---- overlapped reduce of PREVIOUS superstep (24-FMA W2 dot) ----
        if (s > 0 && tid < 384) {
            int t = tid & 63, k = tid >> 6;
            int pp = (s - 1) & 1;
            const float* wk = &w2s[k * 24];
            const float* rp0 = &red[pp][0][t * 25];
            float a0 = 0.f;
            #pragma unroll
            for (int j = 0; j < 24; ++j) a0 = fmaf(rp0[j], wk[j], a0);
            out[((size_t)b * TT + (w0 - 2) * 64 + t) * 6 + k] = a0;
            const float* rp1 = &red[pp][1][t * 25];
            float a1 = 0.f;
            #pragma unroll
            for (int j = 0; j < 24; ++j) a1 = fmaf(rp1[j], wk[j], a1);
            out[((size_t)b * TT + (w1 - 2) * 64 + t) * 6 + k] = a1;
        }

        // ---- stage next superstep's x (ring slots freed last superstep) ----
        if (have) {
            int t = tid >> 3, c = tid & 7;
            *(float4*)&xs[(w0 + 2) & 3][t * 36 + 4 * c] = nv0;
            *(float4*)&xs[(w1 + 2) & 3][t * 36 + 4 * c] = nv1;
        }
        __syncthreads();   // the ONLY barrier per superstep
    }

    // epilogue: reduce superstep 15 (windows 30, 31)
    if (tid < 384) {
        int t = tid & 63, k = tid >> 6;
        const float* wk = &w2s[k * 24];
        const float* rp0 = &red[1][0][t * 25];
        float a0 = 0.f;
        #pragma unroll
        for (int j = 0; j < 24; ++j) a0 = fmaf(rp0[j], wk[j], a0);
        out[((size_t)b * TT + 30 * 64 + t) * 6 + k] = a0;
        const float* rp1 = &red[1][1][t * 25];
        float a1 = 0.f;
        #pragma unroll
        for (int j = 0; j < 24; ++j) a1 = fmaf(rp1[j], wk[j], a1);
        out[((size_t)b * TT + 31 * 64 + t) * 6 + k] = a1;
    }
}

extern "C" void kernel_launch(void* const* d_in, const int* in_sizes, int n_in,
                              void* d_out, int out_size, void* d_ws, size_t ws_size,
                              hipStream_t stream)
{
    const float* x   = (const float*)d_in[0];
    const float* W11 = (const float*)d_in[1];
    const float* W12 = (const float*)d_in[2];
    const float* W2  = (const float*)d_in[3];
    float* out = (float*)d_out;

    hipLaunchKernelGGL(k_fused, dim3(BT), dim3(512), 0, stream,
                       x, W11, W12, W2, out);
}

// Round 19
// 120.527 us; speedup vs baseline: 4.4716x; 1.0272x over previous
//
#include <hip/hip_runtime.h>
#include <math.h>

static constexpr int BT  = 512;    // batch
static constexpr int TT  = 2048;   // time steps

// f64-derived constants, cast to f32 exactly as the reference does
static constexpr float C00 = (float)(1000.0 / (1.0 - 0.09));            // D[0][0]
static constexpr float C01 = (float)((1000.0 / (1.0 - 0.09)) * 0.3);    // D[0][1]
static constexpr float C22 = (float)((1000.0 / (1.0 - 0.09)) * 0.35);   // D[2][2]
static constexpr float INV3GH = (float)(1.0 / (3.0 * (1000.0 / 2.6) + 100.0));
static constexpr float K2  = (float)(100.0 / (3.0 * (1000.0 / 2.6) + 100.0)); // H/(3G+H)
static constexpr float SQ3 = 1.7320508075688772f;
static constexpr float IR3 = 0.57735026918962576f;

typedef float f2 __attribute__((ext_vector_type(2)));

__device__ __forceinline__ float softplus_f(float v) {
    return fmaxf(v, 0.0f) + log1pf(expf(-fabsf(v)));
}

// Ballot-driven plastic window. R19: 3 shfls per event (qs reconstructed
// bit-identically from sxs/sys/sps), K2-folded hardening update.
__device__ __forceinline__ void plastic_window(
    float e0, float e1, float e2, int lane,
    float& Pxx, float& Pyy, float& Pxy, float& sigY, float& sigY2,
    float& sxx, float& syy, float& sxy, float& f)
{
    sxx = e0 - Pxx; syy = e1 - Pyy; sxy = e2 - Pxy;
    float q = fmaf(sxy, sxy, 1e-12f);   // sxy sqrt3-scaled
    q = fmaf(syy, syy, q);
    q = fmaf(sxx, sxx - syy, q);
    f = 1.0f;
    unsigned long long mask = __ballot(q > sigY2);
    while (mask) {
        int ts = __ffsll((long long)mask) - 1;
        float sxs = __shfl(sxx, ts);
        float sys = __shfl(syy, ts);
        float sps = __shfl(sxy, ts);
        float qs  = fmaf(sps, sps, 1e-12f);      // == lane ts's q (same FMA seq)
        qs = fmaf(sys, sys, qs);
        qs = fmaf(sxs, sxs - sys, qs);
        float rq  = __builtin_amdgcn_rsqf(qs);
        float seq = qs * rq;
        float fn  = fmaf(K2, seq - sigY, sigY);  // new sigY (seq > sigY at event)
        float fs  = fn * rq;
        float om  = 1.0f - fs;
        Pxx = fmaf(om, sxs, Pxx);
        Pyy = fmaf(om, sys, Pyy);
        Pxy = fmaf(om, sps, Pxy);
        sigY = fn; sigY2 = fn * fn;
        if (lane == ts) f = fs;
        bool redo = lane > ts;
        if (redo) {
            sxx = e0 - Pxx; syy = e1 - Pyy; sxy = e2 - Pxy;
            q = fmaf(sxy, sxy, 1e-12f);
            q = fmaf(syy, syy, q);
            q = fmaf(sxx, sxx - syy, q);
        }
        mask = __ballot(redo && (q > sigY2));
    }
}

// ---------------------------------------------------------------------------
// R19 = R15 (verified best structure: LDS-staged x 4-ring, 2-window superstep,
// shared weight reads, interleaved damage scans, w2r partials, 2 barriers)
// + leaner event loop (above) + coalesced reduce mapping (t=tid/6, k=tid%6).
// ---------------------------------------------------------------------------
__global__ __launch_bounds__(512) void k_fused(
    const float* __restrict__ x, const float* __restrict__ W11,
    const float* __restrict__ W12, const float* __restrict__ W2,
    float* __restrict__ out)
{
    __shared__ __align__(16) float w11s[16 * 36];   // [2p+h][36]
    __shared__ __align__(16) float w12d[24 * 36];   // [3p+j][36], D & sqrt3 folded
    __shared__ float w2s[144];                      // softplus(W2), xy col * IR3
    __shared__ __align__(16) float xs[4][64 * 36];  // 4-deep x window ring
    __shared__ float red[2][64 * 51];               // [win][t*51 + k*8 + p]

    const int tid  = threadIdx.x;
    const int lane = tid & 63;     // t within window
    const int wv   = tid >> 6;     // p (0..7)
    const int b    = blockIdx.x;

    // ---- prologue: weights into LDS ----
    if (tid < 512) w11s[(tid >> 5) * 36 + (tid & 31)] = W11[tid];
    if (tid < 256) {
        int i = tid + 512;
        w11s[(i >> 5) * 36 + (i & 31)] = W11[i];
    }
    for (int i = tid; i < 768; i += 512) {
        int r = i >> 5, fc = i & 31;
        int p = r / 3, j = r - p * 3;
        const float* wb = W12 + p * 96 + fc;
        float v;
        if (j == 0)      v = C00 * wb[0]  + C01 * wb[32];
        else if (j == 1) v = C01 * wb[0]  + C00 * wb[32];
        else             v = (C22 * wb[64]) * SQ3;
        w12d[r * 36 + fc] = v;
    }
    if (tid < 144) {
        float v = softplus_f(W2[tid]);
        if ((tid % 24) % 3 == 2) v *= IR3;
        w2s[tid] = v;
    }
    // stage windows 0 and 1
    const float4* xg4 = (const float4*)x + (size_t)b * (TT * 8);
    {
        int t = tid >> 3, c = tid & 7;
        float4 v0 = xg4[tid];
        float4 v1 = xg4[512 + tid];
        *(float4*)&xs[0][t * 36 + 4 * c] = v0;
        *(float4*)&xs[1][t * 36 + 4 * c] = v1;
    }
    __syncthreads();

    // wave-uniform W2 columns for this p
    float w2r0[6], w2r1[6], w2r2[6];
    #pragma unroll
    for (int k = 0; k < 6; ++k) {
        w2r0[k] = w2s[k * 24 + 3 * wv];
        w2r1[k] = w2s[k * 24 + 3 * wv + 1];
        w2r2[k] = w2s[k * 24 + 3 * wv + 2];
    }
    const float4* wa0 = (const float4*)(w11s + (2 * wv) * 36);
    const float4* wa1 = (const float4*)(w11s + (2 * wv + 1) * 36);
    const float4* wb0 = (const float4*)(w12d + (3 * wv) * 36);
    const float4* wb1 = (const float4*)(w12d + (3 * wv + 1) * 36);
    const float4* wb2 = (const float4*)(w12d + (3 * wv + 2) * 36);

    // coalesced reduce mapping: thread -> (t, k) with k fastest
    const int rt = tid / 6, rk = tid - 6 * (tid / 6);

    float Pxx = 0.f, Pyy = 0.f, Pxy = 0.f;
    float sigY = 10.f, sigY2 = 100.f, d0 = 0.f;

    for (int s = 0; s < 16; ++s) {
        const int w0 = 2 * s, w1 = w0 + 1;
        const bool have = (s < 15);
        float4 nv0, nv1;
        if (have) {
            nv0 = xg4[(w0 + 2) * 512 + tid];
            nv1 = xg4[(w1 + 2) * 512 + tid];
        }

        // ---- projection of BOTH windows, shared weight reads ----
        const float* xr0 = &xs[w0 & 3][lane * 36];
        const float* xr1 = &xs[w1 & 3][lane * 36];
        f2 dnA = {0,0}, dsA = {0,0}, e0A = {0,0}, e1A = {0,0}, e2A = {0,0};
        f2 dnB = {0,0}, dsB = {0,0}, e0B = {0,0}, e1B = {0,0}, e2B = {0,0};
        #pragma unroll
        for (int c = 0; c < 8; ++c) {
            float4 a0 = wa0[c], a1 = wa1[c];
            float4 b0 = wb0[c], b1 = wb1[c], b2 = wb2[c];
            float4 xf0 = *(const float4*)(xr0 + 4 * c);
            float4 xf1 = *(const float4*)(xr1 + 4 * c);
            f2 xlo0 = {xf0.x, xf0.y}, xhi0 = {xf0.z, xf0.w};
            f2 xlo1 = {xf1.x, xf1.y}, xhi1 = {xf1.z, xf1.w};
            f2 t0, t1;
            t0 = (f2){a0.x, a0.y}; t1 = (f2){a0.z, a0.w};
            dnA = xlo0 * t0 + dnA;  dnA = xhi0 * t1 + dnA;
            dnB = xlo1 * t0 + dnB;  dnB = xhi1 * t1 + dnB;
            t0 = (f2){a1.x, a1.y}; t1 = (f2){a1.z, a1.w};
            dsA = xlo0 * t0 + dsA;  dsA = xhi0 * t1 + dsA;
            dsB = xlo1 * t0 + dsB;  dsB = xhi1 * t1 + dsB;
            t0 = (f2){b0.x, b0.y}; t1 = (f2){b0.z, b0.w};
            e0A = xlo0 * t0 + e0A;  e0A = xhi0 * t1 + e0A;
            e0B = xlo1 * t0 + e0B;  e0B = xhi1 * t1 + e0B;
            t0 = (f2){b1.x, b1.y}; t1 = (f2){b1.z, b1.w};
            e1A = xlo0 * t0 + e1A;  e1A = xhi0 * t1 + e1A;
            e1B = xlo1 * t0 + e1B;  e1B = xhi1 * t1 + e1B;
            t0 = (f2){b2.x, b2.y}; t1 = (f2){b2.z, b2.w};
            e2A = xlo0 * t0 + e2A;  e2A = xhi0 * t1 + e2A;
            e2B = xlo1 * t0 + e2B;  e2B = xhi1 * t1 + e2B;
        }
        float dn0 = dnA.x + dnA.y, ds0 = dsA.x + dsA.y;
        float e00 = e0A.x + e0A.y, e10 = e1A.x + e1A.y, e20 = e2A.x + e2A.y;
        float dn1 = dnB.x + dnB.y, ds1 = dsB.x + dsB.y;
        float e01 = e0B.x + e0B.y, e11 = e1B.x + e1B.y, e21 = e2B.x + e2B.y;

        float dnp0  = fmaxf(dn0, 0.f);
        float lam0  = sqrtf(fmaf(dnp0, dnp0, fmaf(ds0, ds0, 1e-12f)));
        float dnew0 = (0.1f * (lam0 - 0.01f)) / (lam0 * 0.09f);
        dnew0 = fminf(fmaxf(dnew0, 0.f), 1.f);
        float dnp1  = fmaxf(dn1, 0.f);
        float lam1  = sqrtf(fmaf(dnp1, dnp1, fmaf(ds1, ds1, 1e-12f)));
        float dnew1 = (0.1f * (lam1 - 0.01f)) / (lam1 * 0.09f);
        dnew1 = fminf(fmaxf(dnew1, 0.f), 1.f);

        // ---- damage max-scans, two windows interleaved (2x ILP) ----
        float m0 = dnew0, m1 = dnew1;
        #pragma unroll
        for (int off = 1; off < 64; off <<= 1) {
            float t0 = __shfl_up(m0, off);
            float t1 = __shfl_up(m1, off);
            if (lane >= off) { m0 = fmaxf(m0, t0); m1 = fmaxf(m1, t1); }
        }
        float de0 = __shfl_up(m0, 1);
        de0 = (lane == 0) ? d0 : fmaxf(d0, de0);
        bool loading0 = dnew0 > de0;
        float di0 = fmaxf(de0, dnew0);
        float d0a = fmaxf(d0, __shfl(m0, 63));     // d after window w0
        float de1 = __shfl_up(m1, 1);
        de1 = (lane == 0) ? d0a : fmaxf(d0a, de1);
        bool loading1 = dnew1 > de1;
        float di1 = fmaxf(de1, dnew1);
        d0 = fmaxf(d0a, __shfl(m1, 63));

        // ---- plastic loops, exact serial order: w0 fully before w1 ----
        float sxx0, syy0, sxy0, f0;
        plastic_window(e00, e10, e20, lane, Pxx, Pyy, Pxy, sigY, sigY2,
                       sxx0, syy0, sxy0, f0);
        float scale0 = loading0 ? f0 : f0 * (1.0f - di0);
        float o00 = scale0 * sxx0, o10 = scale0 * syy0, o20 = scale0 * sxy0;

        float sxx1, syy1, sxy1, f1;
        plastic_window(e01, e11, e21, lane, Pxx, Pyy, Pxy, sigY, sigY2,
                       sxx1, syy1, sxy1, f1);
        float scale1 = loading1 ? f1 : f1 * (1.0f - di1);
        float o01 = scale1 * sxx1, o11 = scale1 * syy1, o21 = scale1 * sxy1;

        // ---- per-wave W2 partials for both windows ----
        #pragma unroll
        for (int k = 0; k < 6; ++k) {
            float c0 = fmaf(o00, w2r0[k], fmaf(o10, w2r1[k], o20 * w2r2[k]));
            float c1 = fmaf(o01, w2r0[k], fmaf(o11, w2r1[k], o21 * w2r2[k]));
            red[0][lane * 51 + k * 8 + wv] = c0;
            red[1][lane * 51 + k * 8 + wv] = c1;
        }
        __syncthreads();

        // ---- reduce both windows (coalesced out writes) + stage next x ----
        if (tid < 384) {
            const float* rp0 = &red[0][rt * 51 + rk * 8];
            float a0 = ((rp0[0] + rp0[1]) + (rp0[2] + rp0[3]))
                     + ((rp0[4] + rp0[5]) + (rp0[6] + rp0[7]));
            out[((size_t)b * TT + w0 * 64 + rt) * 6 + rk] = a0;
            const float* rp1 = &red[1][rt * 51 + rk * 8];
            float a1 = ((rp1[0] + rp1[1]) + (rp1[2] + rp1[3]))
                     + ((rp1[4] + rp1[5]) + (rp1[6] + rp1[7]));
            out[((size_t)b * TT + w1 * 64 + rt) * 6 + rk] = a1;
        }
        if (have) {
            int t = tid >> 3, c = tid & 7;
            *(float4*)&xs[(w0 + 2) & 3][t * 36 + 4 * c] = nv0;
            *(float4*)&xs[(w1 + 2) & 3][t * 36 + 4 * c] = nv1;
        }
        __syncthreads();
    }
}

extern "C" void kernel_launch(void* const* d_in, const int* in_sizes, int n_in,
                              void* d_out, int out_size, void* d_ws, size_t ws_size,
                              hipStream_t stream)
{
    const float* x   = (const float*)d_in[0];
    const float* W11 = (const float*)d_in[1];
    const float* W12 = (const float*)d_in[2];
    const float* W2  = (const float*)d_in[3];
    float* out = (float*)d_out;

    hipLaunchKernelGGL(k_fused, dim3(BT), dim3(512), 0, stream,
                       x, W11, W12, W2, out);
}